// Round 11
// baseline (469.671 us; speedup 1.0000x reference)
//
#include <hip/hip_runtime.h>
#include <hip/hip_bf16.h>
#include <math.h>

#define SLEN 2048
#define NB 4
#define NH 16
#define DM 1024
#define DH 64

typedef __attribute__((ext_vector_type(8))) short bf16x8;
typedef __attribute__((ext_vector_type(8))) unsigned short ushort8;
typedef __attribute__((ext_vector_type(4))) unsigned short ushort4v;
typedef __attribute__((ext_vector_type(4))) float f32x4;

#define MFMA16(a, b, c) __builtin_amdgcn_mfma_f32_16x16x32_bf16((a), (b), (c), 0, 0, 0)

__device__ __forceinline__ unsigned short f2b(float f) {
    unsigned u = __builtin_bit_cast(unsigned, f);
    u = (u + 0x7FFFu + ((u >> 16) & 1u)) >> 16;
    return (unsigned short)u;
}

__device__ __forceinline__ float b2f(unsigned short h) {
    return __builtin_bit_cast(float, (unsigned)h << 16);
}

__device__ __forceinline__ void gload16(const unsigned short* g, unsigned short* l) {
    __builtin_amdgcn_global_load_lds((const __attribute__((address_space(1))) unsigned int*)g,
                                     (__attribute__((address_space(3))) unsigned int*)l,
                                     16, 0, 0);
}

// ---------------- 4 weight transposes in one launch: fp32 [K][N] -> bf16 [N][K] ----------------
__global__ __launch_bounds__(256) void wtrans4(const float* __restrict__ w0,
                                               const float* __restrict__ w1,
                                               const float* __restrict__ w2,
                                               const float* __restrict__ w3,
                                               unsigned short* __restrict__ outBase) {
    int z = blockIdx.z;
    const float* in = (z == 0) ? w0 : (z == 1) ? w1 : (z == 2) ? w2 : w3;
    unsigned short* out = outBase + (size_t)z * DM * DM;
    // fold 1/sqrt(H*dk) AND log2(e) into Wq: scores come out in log2 domain
    float scale = (z == 0) ? (1.4426950408889634f / 32.f) : 1.f;
    __shared__ float tile[32][33];
    int k0 = blockIdx.y * 32, n0 = blockIdx.x * 32;
    int tx = threadIdx.x & 31, ty = threadIdx.x >> 5;
    for (int i = ty; i < 32; i += 8) tile[i][tx] = in[(size_t)(k0 + i) * DM + n0 + tx];
    __syncthreads();
    for (int i = ty; i < 32; i += 8) out[(size_t)(n0 + i) * DM + k0 + tx] = f2b(tile[tx][i] * scale);
}

// ---------------- QKV projection GEMM: A fp32 (reg-staged, prefetched), B bf16 gload_lds ----------
// z = bid>>9 selects (q,k,v). z==2 (V) computes C^T via swapped MFMA operands and stores
// VT2[d=0..1023][b*2048+s] so the separate V head-transpose kernel is eliminated.
__global__ __launch_bounds__(256) void gemm_qkv(const float* __restrict__ Aq,
                                                const float* __restrict__ Ak,
                                                const float* __restrict__ Av,
                                                const unsigned short* __restrict__ B0,
                                                unsigned short* __restrict__ C0) {
    const size_t WSZ = (size_t)DM * DM;
    const size_t MSZ = (size_t)NB * SLEN * DM;
    __shared__ __align__(16) unsigned short As[128 * 64];
    __shared__ __align__(16) unsigned short Bs[128 * 64];
    int bid = blockIdx.x;
    int z = bid >> 9, inner = bid & 511;
    const float* Af = (z == 0) ? Aq : (z == 1) ? Ak : Av;
    const unsigned short* Bt = B0 + (size_t)z * WSZ;
    unsigned short* C = C0 + (size_t)z * MSZ;
    bool ct = (z == 2);
    int m0 = (inner >> 3) * 128, n0 = (inner & 7) * 128;
    int t = threadIdx.x, lane = t & 63, w = t >> 6;
    int wm = (w >> 1) * 64, wn = (w & 1) * 64;
    int lr = lane & 15, hi = lane >> 4, lk = hi * 8, lq = hi * 4;
    int srow = w * 8 + (lane >> 3);     // + c*32
    int scol = (lane & 7) * 8;
    f32x4 acc[4][4] = {};
    // prefetch A (fp32) for kt=0
    float4 pf[4][2];
#pragma unroll
    for (int c = 0; c < 4; c++) {
        const float* ap = &Af[(size_t)(m0 + c * 32 + srow) * DM + scol];
        pf[c][0] = ((const float4*)ap)[0];
        pf[c][1] = ((const float4*)ap)[1];
    }
    for (int kt = 0; kt < DM; kt += 64) {
        __syncthreads();
#pragma unroll
        for (int c = 0; c < 4; c++) {
            int row = c * 32 + srow;
            float4 f0 = pf[c][0], f1 = pf[c][1];
            ushort8 h = {f2b(f0.x), f2b(f0.y), f2b(f0.z), f2b(f0.w),
                         f2b(f1.x), f2b(f1.y), f2b(f1.z), f2b(f1.w)};
            *(ushort8*)&As[row * 64 + scol] = h;
            gload16(&Bt[(size_t)(n0 + row) * DM + kt + scol], &Bs[(c * 4 + w) * 512]);
        }
        __syncthreads();
        if (kt + 64 < DM) {
#pragma unroll
            for (int c = 0; c < 4; c++) {
                const float* ap = &Af[(size_t)(m0 + c * 32 + srow) * DM + kt + 64 + scol];
                pf[c][0] = ((const float4*)ap)[0];
                pf[c][1] = ((const float4*)ap)[1];
            }
        }
        if (ct) {
#pragma unroll
            for (int ks = 0; ks < 2; ks++) {
                bf16x8 a[4], b[4];
#pragma unroll
                for (int mt = 0; mt < 4; mt++) a[mt] = *(const bf16x8*)&As[(wm + mt * 16 + lr) * 64 + ks * 32 + lk];
#pragma unroll
                for (int nt = 0; nt < 4; nt++) b[nt] = *(const bf16x8*)&Bs[(wn + nt * 16 + lr) * 64 + ks * 32 + lk];
#pragma unroll
                for (int mt = 0; mt < 4; mt++)
#pragma unroll
                    for (int nt = 0; nt < 4; nt++) acc[mt][nt] = MFMA16(b[nt], a[mt], acc[mt][nt]);
            }
        } else {
#pragma unroll
            for (int ks = 0; ks < 2; ks++) {
                bf16x8 a[4], b[4];
#pragma unroll
                for (int mt = 0; mt < 4; mt++) a[mt] = *(const bf16x8*)&As[(wm + mt * 16 + lr) * 64 + ks * 32 + lk];
#pragma unroll
                for (int nt = 0; nt < 4; nt++) b[nt] = *(const bf16x8*)&Bs[(wn + nt * 16 + lr) * 64 + ks * 32 + lk];
#pragma unroll
                for (int mt = 0; mt < 4; mt++)
#pragma unroll
                    for (int nt = 0; nt < 4; nt++) acc[mt][nt] = MFMA16(a[mt], b[nt], acc[mt][nt]);
            }
        }
    }
    if (ct) {
        // C^T: rows = d (n-side), cols = b*S+s (m-side); width NB*SLEN
#pragma unroll
        for (int mt = 0; mt < 4; mt++)
#pragma unroll
            for (int nt = 0; nt < 4; nt++)
#pragma unroll
                for (int r = 0; r < 4; r++) {
                    int rr = n0 + wn + nt * 16 + lq + r;
                    int cc = m0 + wm + mt * 16 + lr;
                    C[(size_t)rr * (NB * SLEN) + cc] = f2b(acc[mt][nt][r]);
                }
    } else {
#pragma unroll
        for (int mt = 0; mt < 4; mt++)
#pragma unroll
            for (int nt = 0; nt < 4; nt++)
#pragma unroll
                for (int r = 0; r < 4; r++) {
                    int rr = m0 + wm + mt * 16 + lq + r;
                    int cc = n0 + wn + nt * 16 + lr;
                    C[(size_t)rr * DM + cc] = f2b(acc[mt][nt][r]);
                }
    }
}

// ---------------- output projection GEMM (m97 structure): A bf16, out fp32 ----------------
__global__ __launch_bounds__(256) void gemm_o(const unsigned short* __restrict__ A,
                                              const unsigned short* __restrict__ Bt,
                                              float* __restrict__ Cf) {
    __shared__ __align__(16) unsigned short As[128 * 64];
    __shared__ __align__(16) unsigned short Bs[128 * 64];
    int inner = blockIdx.x;
    int m0 = (inner >> 3) * 128, n0 = (inner & 7) * 128;
    int t = threadIdx.x, lane = t & 63, w = t >> 6;
    int wm = (w >> 1) * 64, wn = (w & 1) * 64;
    int lr = lane & 15, hi = lane >> 4, lk = hi * 8, lq = hi * 4;
    int srow = w * 8 + (lane >> 3);
    int scol = (lane & 7) * 8;
    f32x4 acc[4][4] = {};
    for (int kt = 0; kt < DM; kt += 64) {
        __syncthreads();
#pragma unroll
        for (int c = 0; c < 4; c++) {
            int row = c * 32 + srow;
            gload16(&A[(size_t)(m0 + row) * DM + kt + scol], &As[(c * 4 + w) * 512]);
            gload16(&Bt[(size_t)(n0 + row) * DM + kt + scol], &Bs[(c * 4 + w) * 512]);
        }
        __syncthreads();
#pragma unroll
        for (int ks = 0; ks < 2; ks++) {
            bf16x8 a[4], b[4];
#pragma unroll
            for (int mt = 0; mt < 4; mt++) a[mt] = *(const bf16x8*)&As[(wm + mt * 16 + lr) * 64 + ks * 32 + lk];
#pragma unroll
            for (int nt = 0; nt < 4; nt++) b[nt] = *(const bf16x8*)&Bs[(wn + nt * 16 + lr) * 64 + ks * 32 + lk];
#pragma unroll
            for (int mt = 0; mt < 4; mt++)
#pragma unroll
                for (int nt = 0; nt < 4; nt++) acc[mt][nt] = MFMA16(a[mt], b[nt], acc[mt][nt]);
        }
    }
#pragma unroll
    for (int mt = 0; mt < 4; mt++)
#pragma unroll
        for (int nt = 0; nt < 4; nt++)
#pragma unroll
            for (int r = 0; r < 4; r++) {
                int rr = m0 + wm + mt * 16 + lq + r;
                int cc = n0 + wn + nt * 16 + lr;
                Cf[(size_t)rr * DM + cc] = acc[mt][nt][r];
            }
}

// ---------------- fused causal attention: QBLK=128, 8 waves, log2-domain softmax ----------------
// R8 structure; V read from VT2 [d][b*2048+s] (stride NB*SLEN).
__global__ __launch_bounds__(512) void attn_kernel(const unsigned short* __restrict__ Qh,
                                                   const unsigned short* __restrict__ Kh,
                                                   const unsigned short* __restrict__ Vt,
                                                   float* __restrict__ attn_out,
                                                   unsigned short* __restrict__ O) {
    int bx = blockIdx.x;
    int qt = bx >> 6, bh = bx & 63;   // same-bh blocks share XCD (bid%8 == bh%8)
    int b = bh >> 4, h = bh & 15;
    int q0 = qt * 128;
    int t = threadIdx.x, lane = t & 63, w = t >> 6;      // 8 waves
    int lr = lane & 15, hi = lane >> 4, lk = hi * 8, lq = hi * 4;
    __shared__ __align__(16) unsigned short Ks[2][64 * 72];
    __shared__ __align__(16) unsigned short Vs[64 * 72];
    __shared__ __align__(16) unsigned short Ps[8][16 * 72];

    int qrow = q0 + w * 16 + lr;
    bf16x8 aq0 = *(const bf16x8*)&Qh[(size_t)(b * SLEN + qrow) * DM + h * 64 + lk];
    bf16x8 aq1 = *(const bf16x8*)&Qh[(size_t)(b * SLEN + qrow) * DM + h * 64 + 32 + lk];

    int srow = t >> 3, sseg = (t & 7) * 8;    // 512 threads stage one 64x64 tile
    int ntile = 2 * qt + 2;                   // always even
    int nfull = (q0 + w * 16 + 1) >> 6;         // tiles fully unmasked for this wave
    int nact  = ((q0 + w * 16 + 15) >> 6) + 1;  // tiles with any active key (<= ntile)
    const unsigned short* Kbase = &Kh[(size_t)(b * SLEN + srow) * DM + h * 64 + sseg];
    const unsigned short* Vbase = &Vt[(size_t)(h * 64 + srow) * (NB * SLEN) + b * SLEN + sseg];

    float rowsum = 0.f;

    // ---- pass 1: row sums of 2^s; K double-buffered, 1 barrier/iter, reg prefetch ----
    ushort8 kreg = *(const ushort8*)&Kbase[0];
    for (int j = 0; j < ntile; j++) {
        ushort8 knext{};
        if (j + 1 < ntile) knext = *(const ushort8*)&Kbase[(size_t)(j + 1) * 64 * DM];
        *(ushort8*)&Ks[j & 1][srow * 72 + sseg] = kreg;
        __syncthreads();
        kreg = knext;
        if (j < nact) {
            const unsigned short* Kb = Ks[j & 1];
            if (j < nfull) {
#pragma unroll
                for (int nt = 0; nt < 4; nt++) {
                    f32x4 acc = {0.f, 0.f, 0.f, 0.f};
                    bf16x8 b0 = *(const bf16x8*)&Kb[(nt * 16 + lr) * 72 + lk];
                    bf16x8 b1 = *(const bf16x8*)&Kb[(nt * 16 + lr) * 72 + 32 + lk];
                    acc = MFMA16(b0, aq0, acc);
                    acc = MFMA16(b1, aq1, acc);
#pragma unroll
                    for (int r = 0; r < 4; r++) rowsum += exp2f(acc[r]);
                }
            } else {
#pragma unroll
                for (int nt = 0; nt < 4; nt++) {
                    f32x4 acc = {0.f, 0.f, 0.f, 0.f};
                    bf16x8 b0 = *(const bf16x8*)&Kb[(nt * 16 + lr) * 72 + lk];
                    bf16x8 b1 = *(const bf16x8*)&Kb[(nt * 16 + lr) * 72 + 32 + lk];
                    acc = MFMA16(b0, aq0, acc);
                    acc = MFMA16(b1, aq1, acc);
#pragma unroll
                    for (int r = 0; r < 4; r++) {
                        int key = j * 64 + nt * 16 + lq + r;
                        if (key <= qrow) rowsum += exp2f(acc[r]);
                    }
                }
            }
        }
    }
    rowsum += __shfl_xor(rowsum, 16);
    rowsum += __shfl_xor(rowsum, 32);
    float nlg = -log2f(rowsum);
    f32x4 cinit = {nlg, nlg, nlg, nlg};

    // ---- pass 2: P->Ps (bf16) + coalesced attn writes + PV; reg prefetch K+V ----
    f32x4 acco[4] = {};
    kreg = *(const ushort8*)&Kbase[0];
    ushort8 vreg = *(const ushort8*)&Vbase[0];
    for (int j = 0; j < ntile; j++) {
        ushort8 knext{}, vnext{};
        if (j + 1 < ntile) {
            knext = *(const ushort8*)&Kbase[(size_t)(j + 1) * 64 * DM];
            vnext = *(const ushort8*)&Vbase[(j + 1) * 64];
        }
        __syncthreads();   // prev compute done reading Ks[0]/Vs
        *(ushort8*)&Ks[0][srow * 72 + sseg] = kreg;
        *(ushort8*)&Vs[srow * 72 + sseg] = vreg;
        __syncthreads();   // staging visible
        kreg = knext;
        vreg = vnext;
        if (j >= nact) continue;
        bool full = j < nfull;
#pragma unroll
        for (int nt = 0; nt < 4; nt++) {
            f32x4 acc = cinit;
            bf16x8 b0 = *(const bf16x8*)&Ks[0][(nt * 16 + lr) * 72 + lk];
            bf16x8 b1 = *(const bf16x8*)&Ks[0][(nt * 16 + lr) * 72 + 32 + lk];
            acc = MFMA16(b0, aq0, acc);
            acc = MFMA16(b1, aq1, acc);
            ushort4v pb;
            if (full) {
#pragma unroll
                for (int r = 0; r < 4; r++)
                    pb[r] = (unsigned short)(__builtin_bit_cast(unsigned, exp2f(acc[r])) >> 16);
            } else {
#pragma unroll
                for (int r = 0; r < 4; r++) {
                    int key = j * 64 + nt * 16 + lq + r;
                    float p = (key <= qrow) ? exp2f(acc[r]) : 0.f;
                    pb[r] = (unsigned short)(__builtin_bit_cast(unsigned, p) >> 16);
                }
            }
            *(ushort4v*)&Ps[w][lr * 72 + nt * 16 + lq] = pb;
        }
        // ---- coalesced attn store: 16 lanes cover one row's 256B segment; 4 rows/inst ----
        {
            size_t abase = ((size_t)bh * SLEN + q0 + w * 16) * SLEN + j * 64 + lr * 4;
#pragma unroll
            for (int i = 0; i < 4; i++) {
                int row = i * 4 + hi;
                ushort4v pb4 = *(const ushort4v*)&Ps[w][row * 72 + lr * 4];
                f32x4 pf = {b2f(pb4[0]), b2f(pb4[1]), b2f(pb4[2]), b2f(pb4[3])};
                __builtin_nontemporal_store(pf, (f32x4*)&attn_out[abase + (size_t)row * SLEN]);
            }
        }
        // Ps per-wave private: in-wave ds ordering suffices (no barrier)
        bf16x8 pa0 = *(const bf16x8*)&Ps[w][lr * 72 + lk];
        bf16x8 pa1 = *(const bf16x8*)&Ps[w][lr * 72 + 32 + lk];
#pragma unroll
        for (int nt = 0; nt < 4; nt++) {
            bf16x8 bv0 = *(const bf16x8*)&Vs[(nt * 16 + lr) * 72 + lk];
            bf16x8 bv1 = *(const bf16x8*)&Vs[(nt * 16 + lr) * 72 + 32 + lk];
            acco[nt] = MFMA16(pa0, bv0, acco[nt]);
            acco[nt] = MFMA16(pa1, bv1, acco[nt]);
        }
    }

    // ---- zero-fill masked region per wave (keys >= nact*64) ----
    int kz = nact * 64;
    if (kz < SLEN) {
        int n4 = (SLEN - kz) >> 2;
        f32x4 z4 = {0.f, 0.f, 0.f, 0.f};
        for (int rr = 0; rr < 16; rr++) {
            int qr = q0 + w * 16 + rr;
            f32x4* dst = (f32x4*)&attn_out[((size_t)bh * SLEN + qr) * SLEN + kz];
            for (int i = lane; i < n4; i += 64) __builtin_nontemporal_store(z4, &dst[i]);
        }
    }

    // ---- O epilogue (acco: row=q=lq+r, col=d=lr); p already normalized ----
#pragma unroll
    for (int nt = 0; nt < 4; nt++)
#pragma unroll
        for (int r = 0; r < 4; r++) {
            int qr = q0 + w * 16 + lq + r;
            O[(size_t)(b * SLEN + qr) * DM + h * 64 + nt * 16 + lr] = f2b(acco[nt][r]);
        }
}

extern "C" void kernel_launch(void* const* d_in, const int* in_sizes, int n_in,
                              void* d_out, int out_size, void* d_ws, size_t ws_size,
                              hipStream_t stream) {
    const float* q = (const float*)d_in[0];
    const float* k = (const float*)d_in[1];
    const float* v = (const float*)d_in[2];
    const float* Wq = (const float*)d_in[4];
    const float* Wk = (const float*)d_in[5];
    const float* Wv = (const float*)d_in[6];
    const float* Wo = (const float*)d_in[7];

    const size_t WSZ = (size_t)DM * DM;        // 1M elems
    const size_t MSZ = (size_t)NB * SLEN * DM; // 8.4M elems

    // ws (75.5 MB): [WqT WkT WvT WoT][Qh][Kh][VT2][O]
    unsigned short* WqT = (unsigned short*)d_ws;
    unsigned short* WoT = WqT + 3 * WSZ;
    unsigned short* Qh  = WqT + 4 * WSZ;
    unsigned short* Kh  = Qh + MSZ;
    unsigned short* Vt  = Kh + MSZ;   // VT2: [DM][NB*SLEN]
    unsigned short* O   = Vt + MSZ;

    float* out = (float*)d_out;
    float* attn = out + MSZ;

    // 1. weight transposes
    wtrans4<<<dim3(32, 32, 4), 256, 0, stream>>>(Wq, Wk, Wv, Wo, WqT);

    // 2. fused QKV projection (fp32 A direct, V writes C^T): z0->Qh, z1->Kh, z2->VT2
    gemm_qkv<<<1536, 256, 0, stream>>>(q, k, v, WqT, Qh);

    // 3. attention (QBLK=128): attn lower-triangle + zeros + O
    attn_kernel<<<NB * NH * (SLEN / 128), 512, 0, stream>>>(Qh, Kh, Vt, attn, O);

    // 4. output projection
    gemm_o<<<512, 256, 0, stream>>>(O, WoT, out);
}

// Round 12
// 440.938 us; speedup vs baseline: 1.0652x; 1.0652x over previous
//
#include <hip/hip_runtime.h>
#include <hip/hip_bf16.h>
#include <math.h>

#define SLEN 2048
#define NB 4
#define NH 16
#define DM 1024
#define DH 64

typedef __attribute__((ext_vector_type(8))) short bf16x8;
typedef __attribute__((ext_vector_type(8))) unsigned short ushort8;
typedef __attribute__((ext_vector_type(4))) unsigned short ushort4v;
typedef __attribute__((ext_vector_type(4))) float f32x4;

#define MFMA16(a, b, c) __builtin_amdgcn_mfma_f32_16x16x32_bf16((a), (b), (c), 0, 0, 0)

__device__ __forceinline__ unsigned short f2b(float f) {
    unsigned u = __builtin_bit_cast(unsigned, f);
    u = (u + 0x7FFFu + ((u >> 16) & 1u)) >> 16;
    return (unsigned short)u;
}

__device__ __forceinline__ float b2f(unsigned short h) {
    return __builtin_bit_cast(float, (unsigned)h << 16);
}

__device__ __forceinline__ void gload16(const unsigned short* g, unsigned short* l) {
    __builtin_amdgcn_global_load_lds((const __attribute__((address_space(1))) unsigned int*)g,
                                     (__attribute__((address_space(3))) unsigned int*)l,
                                     16, 0, 0);
}

// ---------------- 4 weight transposes in one launch: fp32 [K][N] -> bf16 [N][K] ----------------
__global__ __launch_bounds__(256) void wtrans4(const float* __restrict__ w0,
                                               const float* __restrict__ w1,
                                               const float* __restrict__ w2,
                                               const float* __restrict__ w3,
                                               unsigned short* __restrict__ outBase) {
    int z = blockIdx.z;
    const float* in = (z == 0) ? w0 : (z == 1) ? w1 : (z == 2) ? w2 : w3;
    unsigned short* out = outBase + (size_t)z * DM * DM;
    // fold 1/sqrt(H*dk) AND log2(e) into Wq: scores come out in log2 domain
    float scale = (z == 0) ? (1.4426950408889634f / 32.f) : 1.f;
    __shared__ float tile[32][33];
    int k0 = blockIdx.y * 32, n0 = blockIdx.x * 32;
    int tx = threadIdx.x & 31, ty = threadIdx.x >> 5;
    for (int i = ty; i < 32; i += 8) tile[i][tx] = in[(size_t)(k0 + i) * DM + n0 + tx];
    __syncthreads();
    for (int i = ty; i < 32; i += 8) out[(size_t)(n0 + i) * DM + k0 + tx] = f2b(tile[tx][i] * scale);
}

// ---------------- 3 fp32->bf16 casts in one launch ----------------
__global__ __launch_bounds__(256) void cast3(const float* __restrict__ q,
                                             const float* __restrict__ k,
                                             const float* __restrict__ v,
                                             unsigned short* __restrict__ dstBase, int n8) {
    int z = blockIdx.z;
    const float* in = (z == 0) ? q : (z == 1) ? k : v;
    unsigned short* out = dstBase + (size_t)z * NB * SLEN * DM;
    int stride = gridDim.x * 256;
    for (int i = blockIdx.x * 256 + threadIdx.x; i < n8; i += stride) {
        float4 a = ((const float4*)in)[2 * i];
        float4 b = ((const float4*)in)[2 * i + 1];
        ushort8 h = {f2b(a.x), f2b(a.y), f2b(a.z), f2b(a.w),
                     f2b(b.x), f2b(b.y), f2b(b.z), f2b(b.w)};
        ((ushort8*)out)[i] = h;
    }
}

// ---------------- GEMM (m97 structure), NZ problems by bid>>9; z==2 optionally stores C^T ------
// vct!=0: z==2 uses swapped MFMA operands and stores VT2[d][b*S+s] (kills vtrans).
template <bool OUT_F32>
__global__ __launch_bounds__(256) void gemm_mz(const unsigned short* __restrict__ A0, size_t sA,
                                               const unsigned short* __restrict__ B0, size_t sB,
                                               void* __restrict__ C0, size_t sC,
                                               int N, int K, int vct) {
    __shared__ __align__(16) unsigned short As[128 * 64];
    __shared__ __align__(16) unsigned short Bs[128 * 64];
    int bid = blockIdx.x;
    int z = bid >> 9, inner = bid & 511;
    const unsigned short* A = A0 + (size_t)z * sA;
    const unsigned short* Bt = B0 + (size_t)z * sB;
    bool ct = vct && (z == 2);
    int m0 = (inner >> 3) * 128, n0 = (inner & 7) * 128;
    int t = threadIdx.x, lane = t & 63, w = t >> 6;
    int wm = (w >> 1) * 64, wn = (w & 1) * 64;
    int lr = lane & 15, hi = lane >> 4, lk = hi * 8, lq = hi * 4;
    int srow = w * 8 + (lane >> 3);     // + c*32
    int scol = (lane & 7) * 8;
    f32x4 acc[4][4] = {};
    for (int kt = 0; kt < K; kt += 64) {
        __syncthreads();
#pragma unroll
        for (int c = 0; c < 4; c++) {
            int row = c * 32 + srow;
            gload16(&A[(size_t)(m0 + row) * K + kt + scol], &As[(c * 4 + w) * 512]);
            gload16(&Bt[(size_t)(n0 + row) * K + kt + scol], &Bs[(c * 4 + w) * 512]);
        }
        __syncthreads();
        if (ct) {
#pragma unroll
            for (int ks = 0; ks < 2; ks++) {
                bf16x8 a[4], b[4];
#pragma unroll
                for (int mt = 0; mt < 4; mt++) a[mt] = *(const bf16x8*)&As[(wm + mt * 16 + lr) * 64 + ks * 32 + lk];
#pragma unroll
                for (int nt = 0; nt < 4; nt++) b[nt] = *(const bf16x8*)&Bs[(wn + nt * 16 + lr) * 64 + ks * 32 + lk];
#pragma unroll
                for (int mt = 0; mt < 4; mt++)
#pragma unroll
                    for (int nt = 0; nt < 4; nt++) acc[mt][nt] = MFMA16(b[nt], a[mt], acc[mt][nt]);
            }
        } else {
#pragma unroll
            for (int ks = 0; ks < 2; ks++) {
                bf16x8 a[4], b[4];
#pragma unroll
                for (int mt = 0; mt < 4; mt++) a[mt] = *(const bf16x8*)&As[(wm + mt * 16 + lr) * 64 + ks * 32 + lk];
#pragma unroll
                for (int nt = 0; nt < 4; nt++) b[nt] = *(const bf16x8*)&Bs[(wn + nt * 16 + lr) * 64 + ks * 32 + lk];
#pragma unroll
                for (int mt = 0; mt < 4; mt++)
#pragma unroll
                    for (int nt = 0; nt < 4; nt++) acc[mt][nt] = MFMA16(a[mt], b[nt], acc[mt][nt]);
            }
        }
    }
    if (ct) {
        // C^T: rows = d (n-side), cols = b*S+s (m-side)
        unsigned short* C = (unsigned short*)C0 + (size_t)z * sC;
#pragma unroll
        for (int mt = 0; mt < 4; mt++)
#pragma unroll
            for (int nt = 0; nt < 4; nt++)
#pragma unroll
                for (int r = 0; r < 4; r++) {
                    int rr = n0 + wn + nt * 16 + lq + r;
                    int cc = m0 + wm + mt * 16 + lr;
                    C[(size_t)rr * (NB * SLEN) + cc] = f2b(acc[mt][nt][r]);
                }
    } else {
#pragma unroll
        for (int mt = 0; mt < 4; mt++)
#pragma unroll
            for (int nt = 0; nt < 4; nt++)
#pragma unroll
                for (int r = 0; r < 4; r++) {
                    int rr = m0 + wm + mt * 16 + lq + r;
                    int cc = n0 + wn + nt * 16 + lr;
                    if constexpr (OUT_F32)
                        ((float*)C0 + (size_t)z * sC)[(size_t)rr * N + cc] = acc[mt][nt][r];
                    else
                        ((unsigned short*)C0 + (size_t)z * sC)[(size_t)rr * N + cc] = f2b(acc[mt][nt][r]);
                }
    }
}

// ---------------- fused causal attention: QBLK=128, 8 waves, log2-domain softmax ----------------
// R8 structure; V from VT2 [d][b*S+s] (stride NB*SLEN); LPT order (heavy qt first).
__global__ __launch_bounds__(512) void attn_kernel(const unsigned short* __restrict__ Qh,
                                                   const unsigned short* __restrict__ Kh,
                                                   const unsigned short* __restrict__ Vt,
                                                   float* __restrict__ attn_out,
                                                   unsigned short* __restrict__ O) {
    int bx = blockIdx.x;
    int qt = 15 - (bx >> 6);          // LPT: heaviest tiles dispatch first
    int bh = bx & 63;                 // same-bh blocks share XCD (bid%8 == bh%8)
    int b = bh >> 4, h = bh & 15;
    int q0 = qt * 128;
    int t = threadIdx.x, lane = t & 63, w = t >> 6;      // 8 waves
    int lr = lane & 15, hi = lane >> 4, lk = hi * 8, lq = hi * 4;
    __shared__ __align__(16) unsigned short Ks[2][64 * 72];
    __shared__ __align__(16) unsigned short Vs[64 * 72];
    __shared__ __align__(16) unsigned short Ps[8][16 * 72];

    int qrow = q0 + w * 16 + lr;
    bf16x8 aq0 = *(const bf16x8*)&Qh[(size_t)(b * SLEN + qrow) * DM + h * 64 + lk];
    bf16x8 aq1 = *(const bf16x8*)&Qh[(size_t)(b * SLEN + qrow) * DM + h * 64 + 32 + lk];

    int srow = t >> 3, sseg = (t & 7) * 8;    // 512 threads stage one 64x64 tile
    int ntile = 2 * qt + 2;                   // always even
    int nfull = (q0 + w * 16 + 1) >> 6;         // tiles fully unmasked for this wave
    int nact  = ((q0 + w * 16 + 15) >> 6) + 1;  // tiles with any active key (<= ntile)
    const unsigned short* Kbase = &Kh[(size_t)(b * SLEN + srow) * DM + h * 64 + sseg];
    const unsigned short* Vbase = &Vt[(size_t)(h * 64 + srow) * (NB * SLEN) + b * SLEN + sseg];

    float rowsum = 0.f;

    // ---- pass 1: row sums of 2^s; K double-buffered, 1 barrier/iter, reg prefetch ----
    ushort8 kreg = *(const ushort8*)&Kbase[0];
    for (int j = 0; j < ntile; j++) {
        ushort8 knext{};
        if (j + 1 < ntile) knext = *(const ushort8*)&Kbase[(size_t)(j + 1) * 64 * DM];
        *(ushort8*)&Ks[j & 1][srow * 72 + sseg] = kreg;
        __syncthreads();
        kreg = knext;
        if (j < nact) {
            const unsigned short* Kb = Ks[j & 1];
            if (j < nfull) {
#pragma unroll
                for (int nt = 0; nt < 4; nt++) {
                    f32x4 acc = {0.f, 0.f, 0.f, 0.f};
                    bf16x8 b0 = *(const bf16x8*)&Kb[(nt * 16 + lr) * 72 + lk];
                    bf16x8 b1 = *(const bf16x8*)&Kb[(nt * 16 + lr) * 72 + 32 + lk];
                    acc = MFMA16(b0, aq0, acc);
                    acc = MFMA16(b1, aq1, acc);
#pragma unroll
                    for (int r = 0; r < 4; r++) rowsum += exp2f(acc[r]);
                }
            } else {
#pragma unroll
                for (int nt = 0; nt < 4; nt++) {
                    f32x4 acc = {0.f, 0.f, 0.f, 0.f};
                    bf16x8 b0 = *(const bf16x8*)&Kb[(nt * 16 + lr) * 72 + lk];
                    bf16x8 b1 = *(const bf16x8*)&Kb[(nt * 16 + lr) * 72 + 32 + lk];
                    acc = MFMA16(b0, aq0, acc);
                    acc = MFMA16(b1, aq1, acc);
#pragma unroll
                    for (int r = 0; r < 4; r++) {
                        int key = j * 64 + nt * 16 + lq + r;
                        if (key <= qrow) rowsum += exp2f(acc[r]);
                    }
                }
            }
        }
    }
    rowsum += __shfl_xor(rowsum, 16);
    rowsum += __shfl_xor(rowsum, 32);
    float nlg = -log2f(rowsum);
    f32x4 cinit = {nlg, nlg, nlg, nlg};

    // ---- pass 2: P->Ps (bf16) + coalesced attn writes + PV; reg prefetch K+V ----
    f32x4 acco[4] = {};
    kreg = *(const ushort8*)&Kbase[0];
    ushort8 vreg = *(const ushort8*)&Vbase[0];
    for (int j = 0; j < ntile; j++) {
        ushort8 knext{}, vnext{};
        if (j + 1 < ntile) {
            knext = *(const ushort8*)&Kbase[(size_t)(j + 1) * 64 * DM];
            vnext = *(const ushort8*)&Vbase[(j + 1) * 64];
        }
        __syncthreads();   // prev compute done reading Ks[0]/Vs
        *(ushort8*)&Ks[0][srow * 72 + sseg] = kreg;
        *(ushort8*)&Vs[srow * 72 + sseg] = vreg;
        __syncthreads();   // staging visible
        kreg = knext;
        vreg = vnext;
        if (j >= nact) continue;
        bool full = j < nfull;
#pragma unroll
        for (int nt = 0; nt < 4; nt++) {
            f32x4 acc = cinit;
            bf16x8 b0 = *(const bf16x8*)&Ks[0][(nt * 16 + lr) * 72 + lk];
            bf16x8 b1 = *(const bf16x8*)&Ks[0][(nt * 16 + lr) * 72 + 32 + lk];
            acc = MFMA16(b0, aq0, acc);
            acc = MFMA16(b1, aq1, acc);
            ushort4v pb;
            if (full) {
#pragma unroll
                for (int r = 0; r < 4; r++)
                    pb[r] = (unsigned short)(__builtin_bit_cast(unsigned, exp2f(acc[r])) >> 16);
            } else {
#pragma unroll
                for (int r = 0; r < 4; r++) {
                    int key = j * 64 + nt * 16 + lq + r;
                    float p = (key <= qrow) ? exp2f(acc[r]) : 0.f;
                    pb[r] = (unsigned short)(__builtin_bit_cast(unsigned, p) >> 16);
                }
            }
            *(ushort4v*)&Ps[w][lr * 72 + nt * 16 + lq] = pb;
        }
        // ---- coalesced attn store: 16 lanes cover one row's 256B segment; 4 rows/inst ----
        {
            size_t abase = ((size_t)bh * SLEN + q0 + w * 16) * SLEN + j * 64 + lr * 4;
#pragma unroll
            for (int i = 0; i < 4; i++) {
                int row = i * 4 + hi;
                ushort4v pb4 = *(const ushort4v*)&Ps[w][row * 72 + lr * 4];
                f32x4 pf = {b2f(pb4[0]), b2f(pb4[1]), b2f(pb4[2]), b2f(pb4[3])};
                __builtin_nontemporal_store(pf, (f32x4*)&attn_out[abase + (size_t)row * SLEN]);
            }
        }
        // Ps per-wave private: in-wave ds ordering suffices (no barrier)
        bf16x8 pa0 = *(const bf16x8*)&Ps[w][lr * 72 + lk];
        bf16x8 pa1 = *(const bf16x8*)&Ps[w][lr * 72 + 32 + lk];
#pragma unroll
        for (int nt = 0; nt < 4; nt++) {
            bf16x8 bv0 = *(const bf16x8*)&Vs[(nt * 16 + lr) * 72 + lk];
            bf16x8 bv1 = *(const bf16x8*)&Vs[(nt * 16 + lr) * 72 + 32 + lk];
            acco[nt] = MFMA16(pa0, bv0, acco[nt]);
            acco[nt] = MFMA16(pa1, bv1, acco[nt]);
        }
    }

    // ---- zero-fill masked region per wave (keys >= nact*64) ----
    int kz = nact * 64;
    if (kz < SLEN) {
        int n4 = (SLEN - kz) >> 2;
        f32x4 z4 = {0.f, 0.f, 0.f, 0.f};
        for (int rr = 0; rr < 16; rr++) {
            int qr = q0 + w * 16 + rr;
            f32x4* dst = (f32x4*)&attn_out[((size_t)bh * SLEN + qr) * SLEN + kz];
            for (int i = lane; i < n4; i += 64) __builtin_nontemporal_store(z4, &dst[i]);
        }
    }

    // ---- O epilogue (acco: row=q=lq+r, col=d=lr); p already normalized ----
#pragma unroll
    for (int nt = 0; nt < 4; nt++)
#pragma unroll
        for (int r = 0; r < 4; r++) {
            int qr = q0 + w * 16 + lq + r;
            O[(size_t)(b * SLEN + qr) * DM + h * 64 + nt * 16 + lr] = f2b(acco[nt][r]);
        }
}

extern "C" void kernel_launch(void* const* d_in, const int* in_sizes, int n_in,
                              void* d_out, int out_size, void* d_ws, size_t ws_size,
                              hipStream_t stream) {
    const float* q = (const float*)d_in[0];
    const float* k = (const float*)d_in[1];
    const float* v = (const float*)d_in[2];
    const float* Wq = (const float*)d_in[4];
    const float* Wk = (const float*)d_in[5];
    const float* Wv = (const float*)d_in[6];
    const float* Wo = (const float*)d_in[7];

    const size_t WSZ = (size_t)DM * DM;        // 1M elems
    const size_t MSZ = (size_t)NB * SLEN * DM; // 8.4M elems

    // ws (75.5 MB): [WqT WkT WvT WoT][Qh][Kh][VT2][O]
    unsigned short* WqT = (unsigned short*)d_ws;
    unsigned short* WoT = WqT + 3 * WSZ;
    unsigned short* Qh  = WqT + 4 * WSZ;
    unsigned short* Kh  = Qh + MSZ;
    unsigned short* Vt  = Kh + MSZ;   // VT2: [DM][NB*SLEN]
    unsigned short* O   = Vt + MSZ;

    float* out = (float*)d_out;
    float* attn = out + MSZ;
    // cast scratch in attn region (dead before attn_kernel runs)
    unsigned short* Cq = (unsigned short*)attn;   // q,k,v bf16, contiguous (3*16.8 MB)

    // 1. weight transposes
    wtrans4<<<dim3(32, 32, 4), 256, 0, stream>>>(Wq, Wk, Wv, Wo, WqT);

    // 2. q,k,v casts -> Cq,Cq+MSZ,Cq+2*MSZ
    const int n8 = (int)(MSZ / 8);
    cast3<<<dim3(1024, 1, 3), 256, 0, stream>>>(q, k, v, Cq, n8);

    // 3. fused projection GEMMs (z = bid>>9); z==2 stores V^T directly (vct=1)
    gemm_mz<false><<<1536, 256, 0, stream>>>(Cq, MSZ, WqT, WSZ, (void*)Qh, MSZ, DM, DM, 1);

    // 4. attention (QBLK=128, LPT order): attn lower-triangle + zeros + O
    attn_kernel<<<NB * NH * (SLEN / 128), 512, 0, stream>>>(Qh, Kh, Vt, attn, O);

    // 5. output projection
    gemm_mz<true><<<512, 256, 0, stream>>>(O, 0, WoT, 0, d_out, 0, DM, DM, 0);
}

// Round 13
// 404.536 us; speedup vs baseline: 1.1610x; 1.0900x over previous
//
#include <hip/hip_runtime.h>
#include <hip/hip_bf16.h>
#include <math.h>

#define SLEN 2048
#define NB 4
#define NH 16
#define DM 1024
#define DH 64

typedef __attribute__((ext_vector_type(8))) short bf16x8;
typedef __attribute__((ext_vector_type(8))) unsigned short ushort8;
typedef __attribute__((ext_vector_type(4))) unsigned short ushort4v;
typedef __attribute__((ext_vector_type(4))) float f32x4;

#define MFMA16(a, b, c) __builtin_amdgcn_mfma_f32_16x16x32_bf16((a), (b), (c), 0, 0, 0)

__device__ __forceinline__ unsigned short f2b(float f) {
    unsigned u = __builtin_bit_cast(unsigned, f);
    u = (u + 0x7FFFu + ((u >> 16) & 1u)) >> 16;
    return (unsigned short)u;
}

__device__ __forceinline__ float b2f(unsigned short h) {
    return __builtin_bit_cast(float, (unsigned)h << 16);
}

__device__ __forceinline__ void gload16(const unsigned short* g, unsigned short* l) {
    __builtin_amdgcn_global_load_lds((const __attribute__((address_space(1))) unsigned int*)g,
                                     (__attribute__((address_space(3))) unsigned int*)l,
                                     16, 0, 0);
}

// ---------------- 4 weight transposes in one launch: fp32 [K][N] -> bf16 [N][K] ----------------
__global__ __launch_bounds__(256) void wtrans4(const float* __restrict__ w0,
                                               const float* __restrict__ w1,
                                               const float* __restrict__ w2,
                                               const float* __restrict__ w3,
                                               unsigned short* __restrict__ outBase) {
    int z = blockIdx.z;
    const float* in = (z == 0) ? w0 : (z == 1) ? w1 : (z == 2) ? w2 : w3;
    unsigned short* out = outBase + (size_t)z * DM * DM;
    // fold 1/sqrt(H*dk) AND log2(e) into Wq: scores come out in log2 domain
    float scale = (z == 0) ? (1.4426950408889634f / 32.f) : 1.f;
    __shared__ float tile[32][33];
    int k0 = blockIdx.y * 32, n0 = blockIdx.x * 32;
    int tx = threadIdx.x & 31, ty = threadIdx.x >> 5;
    for (int i = ty; i < 32; i += 8) tile[i][tx] = in[(size_t)(k0 + i) * DM + n0 + tx];
    __syncthreads();
    for (int i = ty; i < 32; i += 8) out[(size_t)(n0 + i) * DM + k0 + tx] = f2b(tile[tx][i] * scale);
}

// ---------------- 3 fp32->bf16 casts in one launch ----------------
__global__ __launch_bounds__(256) void cast3(const float* __restrict__ q,
                                             const float* __restrict__ k,
                                             const float* __restrict__ v,
                                             unsigned short* __restrict__ dstBase, int n8) {
    int z = blockIdx.z;
    const float* in = (z == 0) ? q : (z == 1) ? k : v;
    unsigned short* out = dstBase + (size_t)z * NB * SLEN * DM;
    int stride = gridDim.x * 256;
    for (int i = blockIdx.x * 256 + threadIdx.x; i < n8; i += stride) {
        float4 a = ((const float4*)in)[2 * i];
        float4 b = ((const float4*)in)[2 * i + 1];
        ushort8 h = {f2b(a.x), f2b(a.y), f2b(a.z), f2b(a.w),
                     f2b(b.x), f2b(b.y), f2b(b.z), f2b(b.w)};
        ((ushort8*)out)[i] = h;
    }
}

// ---------------- V head-transpose: Vh bf16 [B*S][DM] -> Vt [BH*DH][S] ----------------
__global__ __launch_bounds__(256) void vtrans(const unsigned short* __restrict__ Vh,
                                              unsigned short* __restrict__ Vt) {
    int bh = blockIdx.y;
    int b = bh >> 4, h = bh & 15;
    int s0 = blockIdx.x * 64;
    __shared__ __align__(16) unsigned short tile[64][72];
    int t = threadIdx.x;
    int r = t >> 2, seg = (t & 3) * 16;
    const ushort8* src = (const ushort8*)&Vh[(size_t)(b * SLEN + s0 + r) * DM + h * 64 + seg];
    *(ushort8*)&tile[r][seg] = src[0];
    *(ushort8*)&tile[r][seg + 8] = src[1];
    __syncthreads();
    unsigned short tmp[16];
#pragma unroll
    for (int i = 0; i < 16; i++) tmp[i] = tile[seg + i][r];
    ushort8 o0, o1;
#pragma unroll
    for (int i = 0; i < 8; i++) { o0[i] = tmp[i]; o1[i] = tmp[8 + i]; }
    unsigned short* dst = &Vt[(size_t)(bh * 64 + r) * SLEN + s0 + seg];
    *(ushort8*)dst = o0;
    *(ushort8*)&dst[8] = o1;
}

// ---------------- GEMM (m97 structure), NZ independent problems by bid>>9 ----------------
template <bool OUT_F32>
__global__ __launch_bounds__(256) void gemm_mz(const unsigned short* __restrict__ A0, size_t sA,
                                               const unsigned short* __restrict__ B0, size_t sB,
                                               void* __restrict__ C0, size_t sC,
                                               int N, int K) {
    __shared__ __align__(16) unsigned short As[128 * 64];
    __shared__ __align__(16) unsigned short Bs[128 * 64];
    int bid = blockIdx.x;
    int z = bid >> 9, inner = bid & 511;
    const unsigned short* A = A0 + (size_t)z * sA;
    const unsigned short* Bt = B0 + (size_t)z * sB;
    int m0 = (inner >> 3) * 128, n0 = (inner & 7) * 128;
    int t = threadIdx.x, lane = t & 63, w = t >> 6;
    int wm = (w >> 1) * 64, wn = (w & 1) * 64;
    int lr = lane & 15, hi = lane >> 4, lk = hi * 8, lq = hi * 4;
    int srow = w * 8 + (lane >> 3);     // + c*32
    int scol = (lane & 7) * 8;
    f32x4 acc[4][4] = {};
    for (int kt = 0; kt < K; kt += 64) {
        __syncthreads();
#pragma unroll
        for (int c = 0; c < 4; c++) {
            int row = c * 32 + srow;
            gload16(&A[(size_t)(m0 + row) * K + kt + scol], &As[(c * 4 + w) * 512]);
            gload16(&Bt[(size_t)(n0 + row) * K + kt + scol], &Bs[(c * 4 + w) * 512]);
        }
        __syncthreads();
#pragma unroll
        for (int ks = 0; ks < 2; ks++) {
            bf16x8 a[4], b[4];
#pragma unroll
            for (int mt = 0; mt < 4; mt++) a[mt] = *(const bf16x8*)&As[(wm + mt * 16 + lr) * 64 + ks * 32 + lk];
#pragma unroll
            for (int nt = 0; nt < 4; nt++) b[nt] = *(const bf16x8*)&Bs[(wn + nt * 16 + lr) * 64 + ks * 32 + lk];
#pragma unroll
            for (int mt = 0; mt < 4; mt++)
#pragma unroll
                for (int nt = 0; nt < 4; nt++) acc[mt][nt] = MFMA16(a[mt], b[nt], acc[mt][nt]);
        }
    }
#pragma unroll
    for (int mt = 0; mt < 4; mt++)
#pragma unroll
        for (int nt = 0; nt < 4; nt++)
#pragma unroll
            for (int r = 0; r < 4; r++) {
                int rr = m0 + wm + mt * 16 + lq + r;
                int cc = n0 + wn + nt * 16 + lr;
                if constexpr (OUT_F32)
                    ((float*)C0 + (size_t)z * sC)[(size_t)rr * N + cc] = acc[mt][nt][r];
                else
                    ((unsigned short*)C0 + (size_t)z * sC)[(size_t)rr * N + cc] = f2b(acc[mt][nt][r]);
            }
}

// ---------------- fused causal attention: QBLK=128, 8 waves, log2-domain softmax ----------------
// Swapped QK^T; P staged bf16 in LDS, attn written via row-coalesced 256B stores.
__global__ __launch_bounds__(512) void attn_kernel(const unsigned short* __restrict__ Qh,
                                                   const unsigned short* __restrict__ Kh,
                                                   const unsigned short* __restrict__ Vt,
                                                   float* __restrict__ attn_out,
                                                   unsigned short* __restrict__ O) {
    int bx = blockIdx.x;
    int qt = bx >> 6, bh = bx & 63;   // same-bh blocks share XCD (bid%8 == bh%8)
    int b = bh >> 4, h = bh & 15;
    int q0 = qt * 128;
    int t = threadIdx.x, lane = t & 63, w = t >> 6;      // 8 waves
    int lr = lane & 15, hi = lane >> 4, lk = hi * 8, lq = hi * 4;
    __shared__ __align__(16) unsigned short Ks[2][64 * 72];
    __shared__ __align__(16) unsigned short Vs[64 * 72];
    __shared__ __align__(16) unsigned short Ps[8][16 * 72];

    int qrow = q0 + w * 16 + lr;
    bf16x8 aq0 = *(const bf16x8*)&Qh[(size_t)(b * SLEN + qrow) * DM + h * 64 + lk];
    bf16x8 aq1 = *(const bf16x8*)&Qh[(size_t)(b * SLEN + qrow) * DM + h * 64 + 32 + lk];

    int srow = t >> 3, sseg = (t & 7) * 8;    // 512 threads stage one 64x64 tile
    int ntile = 2 * qt + 2;                   // always even
    int nfull = (q0 + w * 16 + 1) >> 6;         // tiles fully unmasked for this wave
    int nact  = ((q0 + w * 16 + 15) >> 6) + 1;  // tiles with any active key (<= ntile)
    const unsigned short* Kbase = &Kh[(size_t)(b * SLEN + srow) * DM + h * 64 + sseg];
    const unsigned short* Vbase = &Vt[(size_t)(bh * 64 + srow) * SLEN + sseg];

    float rowsum = 0.f;

    // ---- pass 1: row sums of 2^s; K double-buffered, 1 barrier/iter, reg prefetch ----
    ushort8 kreg = *(const ushort8*)&Kbase[0];
    for (int j = 0; j < ntile; j++) {
        ushort8 knext{};
        if (j + 1 < ntile) knext = *(const ushort8*)&Kbase[(size_t)(j + 1) * 64 * DM];
        *(ushort8*)&Ks[j & 1][srow * 72 + sseg] = kreg;
        __syncthreads();
        kreg = knext;
        if (j < nact) {
            const unsigned short* Kb = Ks[j & 1];
            if (j < nfull) {
#pragma unroll
                for (int nt = 0; nt < 4; nt++) {
                    f32x4 acc = {0.f, 0.f, 0.f, 0.f};
                    bf16x8 b0 = *(const bf16x8*)&Kb[(nt * 16 + lr) * 72 + lk];
                    bf16x8 b1 = *(const bf16x8*)&Kb[(nt * 16 + lr) * 72 + 32 + lk];
                    acc = MFMA16(b0, aq0, acc);
                    acc = MFMA16(b1, aq1, acc);
#pragma unroll
                    for (int r = 0; r < 4; r++) rowsum += exp2f(acc[r]);
                }
            } else {
#pragma unroll
                for (int nt = 0; nt < 4; nt++) {
                    f32x4 acc = {0.f, 0.f, 0.f, 0.f};
                    bf16x8 b0 = *(const bf16x8*)&Kb[(nt * 16 + lr) * 72 + lk];
                    bf16x8 b1 = *(const bf16x8*)&Kb[(nt * 16 + lr) * 72 + 32 + lk];
                    acc = MFMA16(b0, aq0, acc);
                    acc = MFMA16(b1, aq1, acc);
#pragma unroll
                    for (int r = 0; r < 4; r++) {
                        int key = j * 64 + nt * 16 + lq + r;
                        if (key <= qrow) rowsum += exp2f(acc[r]);
                    }
                }
            }
        }
    }
    rowsum += __shfl_xor(rowsum, 16);
    rowsum += __shfl_xor(rowsum, 32);
    float nlg = -log2f(rowsum);
    f32x4 cinit = {nlg, nlg, nlg, nlg};

    // ---- pass 2: P->Ps (bf16) + coalesced attn writes + PV; reg prefetch K+V ----
    f32x4 acco[4] = {};
    kreg = *(const ushort8*)&Kbase[0];
    ushort8 vreg = *(const ushort8*)&Vbase[0];
    for (int j = 0; j < ntile; j++) {
        ushort8 knext{}, vnext{};
        if (j + 1 < ntile) {
            knext = *(const ushort8*)&Kbase[(size_t)(j + 1) * 64 * DM];
            vnext = *(const ushort8*)&Vbase[(j + 1) * 64];
        }
        __syncthreads();   // prev compute done reading Ks[0]/Vs
        *(ushort8*)&Ks[0][srow * 72 + sseg] = kreg;
        *(ushort8*)&Vs[srow * 72 + sseg] = vreg;
        __syncthreads();   // staging visible
        kreg = knext;
        vreg = vnext;
        if (j >= nact) continue;
        bool full = j < nfull;
#pragma unroll
        for (int nt = 0; nt < 4; nt++) {
            f32x4 acc = cinit;
            bf16x8 b0 = *(const bf16x8*)&Ks[0][(nt * 16 + lr) * 72 + lk];
            bf16x8 b1 = *(const bf16x8*)&Ks[0][(nt * 16 + lr) * 72 + 32 + lk];
            acc = MFMA16(b0, aq0, acc);
            acc = MFMA16(b1, aq1, acc);
            ushort4v pb;
            if (full) {
#pragma unroll
                for (int r = 0; r < 4; r++)
                    pb[r] = (unsigned short)(__builtin_bit_cast(unsigned, exp2f(acc[r])) >> 16);
            } else {
#pragma unroll
                for (int r = 0; r < 4; r++) {
                    int key = j * 64 + nt * 16 + lq + r;
                    float p = (key <= qrow) ? exp2f(acc[r]) : 0.f;
                    pb[r] = (unsigned short)(__builtin_bit_cast(unsigned, p) >> 16);
                }
            }
            *(ushort4v*)&Ps[w][lr * 72 + nt * 16 + lq] = pb;
        }
        // ---- coalesced attn store: 16 lanes cover one row's 256B segment; 4 rows/inst ----
        {
            size_t abase = ((size_t)bh * SLEN + q0 + w * 16) * SLEN + j * 64 + lr * 4;
#pragma unroll
            for (int i = 0; i < 4; i++) {
                int row = i * 4 + hi;
                ushort4v pb4 = *(const ushort4v*)&Ps[w][row * 72 + lr * 4];
                f32x4 pf = {b2f(pb4[0]), b2f(pb4[1]), b2f(pb4[2]), b2f(pb4[3])};
                __builtin_nontemporal_store(pf, (f32x4*)&attn_out[abase + (size_t)row * SLEN]);
            }
        }
        // Ps per-wave private: in-wave ds ordering suffices (no barrier)
        bf16x8 pa0 = *(const bf16x8*)&Ps[w][lr * 72 + lk];
        bf16x8 pa1 = *(const bf16x8*)&Ps[w][lr * 72 + 32 + lk];
#pragma unroll
        for (int nt = 0; nt < 4; nt++) {
            bf16x8 bv0 = *(const bf16x8*)&Vs[(nt * 16 + lr) * 72 + lk];
            bf16x8 bv1 = *(const bf16x8*)&Vs[(nt * 16 + lr) * 72 + 32 + lk];
            acco[nt] = MFMA16(pa0, bv0, acco[nt]);
            acco[nt] = MFMA16(pa1, bv1, acco[nt]);
        }
    }

    // ---- zero-fill masked region per wave (keys >= nact*64) ----
    int kz = nact * 64;
    if (kz < SLEN) {
        int n4 = (SLEN - kz) >> 2;
        f32x4 z4 = {0.f, 0.f, 0.f, 0.f};
        for (int rr = 0; rr < 16; rr++) {
            int qr = q0 + w * 16 + rr;
            f32x4* dst = (f32x4*)&attn_out[((size_t)bh * SLEN + qr) * SLEN + kz];
            for (int i = lane; i < n4; i += 64) __builtin_nontemporal_store(z4, &dst[i]);
        }
    }

    // ---- O epilogue (acco: row=q=lq+r, col=d=lr); p already normalized ----
#pragma unroll
    for (int nt = 0; nt < 4; nt++)
#pragma unroll
        for (int r = 0; r < 4; r++) {
            int qr = q0 + w * 16 + lq + r;
            O[(size_t)(b * SLEN + qr) * DM + h * 64 + nt * 16 + lr] = f2b(acco[nt][r]);
        }
}

extern "C" void kernel_launch(void* const* d_in, const int* in_sizes, int n_in,
                              void* d_out, int out_size, void* d_ws, size_t ws_size,
                              hipStream_t stream) {
    const float* q = (const float*)d_in[0];
    const float* k = (const float*)d_in[1];
    const float* v = (const float*)d_in[2];
    const float* Wq = (const float*)d_in[4];
    const float* Wk = (const float*)d_in[5];
    const float* Wv = (const float*)d_in[6];
    const float* Wo = (const float*)d_in[7];

    const size_t WSZ = (size_t)DM * DM;        // 1M elems
    const size_t MSZ = (size_t)NB * SLEN * DM; // 8.4M elems

    // ws (92.3 MB): [WqT WkT WvT WoT][Qh][Kh][Vh][Vt][O]
    unsigned short* WqT = (unsigned short*)d_ws;
    unsigned short* WoT = WqT + 3 * WSZ;
    unsigned short* Qh  = WqT + 4 * WSZ;
    unsigned short* Kh  = Qh + MSZ;
    unsigned short* Vh  = Kh + MSZ;
    unsigned short* Vt  = Vh + MSZ;
    unsigned short* O   = Vt + MSZ;

    float* out = (float*)d_out;
    float* attn = out + MSZ;
    // cast scratch in attn region (dead before attn_kernel runs)
    unsigned short* Cq = (unsigned short*)attn;   // q,k,v bf16, contiguous (3*16.8 MB)

    // 1. weight transposes
    wtrans4<<<dim3(32, 32, 4), 256, 0, stream>>>(Wq, Wk, Wv, Wo, WqT);

    // 2. q,k,v casts -> Cq,Cq+MSZ,Cq+2*MSZ
    const int n8 = (int)(MSZ / 8);
    cast3<<<dim3(1024, 1, 3), 256, 0, stream>>>(q, k, v, Cq, n8);

    // 3. fused projection GEMMs (z = bid>>9)
    gemm_mz<false><<<1536, 256, 0, stream>>>(Cq, MSZ, WqT, WSZ, (void*)Qh, MSZ, DM, DM);

    // 4. V head-transpose
    vtrans<<<dim3(SLEN / 64, NB * NH), 256, 0, stream>>>(Vh, Vt);

    // 5. attention (QBLK=128): attn lower-triangle + zeros + O
    attn_kernel<<<NB * NH * (SLEN / 128), 512, 0, stream>>>(Qh, Kh, Vt, attn, O);

    // 6. output projection
    gemm_mz<true><<<512, 256, 0, stream>>>(O, 0, WoT, 0, d_out, 0, DM, DM);
}